// Round 5
// baseline (205.163 us; speedup 1.0000x reference)
//
#include <hip/hip_runtime.h>

// Problem: B=16, PATCH_NUM=32, PATCH_SIZE=128, H=8, E=64, WIN=4096
// out[b,l,h,e] = V_inter[b, l>>7, h, e] + V_intra[b, l>>5, h, e]
// V_* are full-softmax attentions (scale = 1/8) over L=32 / L=128.
//
// Round 4 -> 5: SINGLE kernel, no workspace.
// Block = (b, h, tile) with tile in [0,4): computes
//   * inter rows pn in [tile*8, tile*8+8)  (disjoint across blocks: 512*8 = 4096
//     = all inter rows -> zero redundant inter compute)
//   * intra rows i in [tile*32, tile*32+32)
//   * writes the 1024 output rows l = i*32+j directly (nontemporal).
// LDS 78.5 KB -> 2 blocks/CU -> all 512 blocks co-resident; the 128 MiB
// store drain (~20 us chip-wide) overlaps all compute.

#define NH 8
#define NE 64
#define ROWSTRIDE (NH * NE)   // 512 floats between consecutive l for fixed (b,h)

typedef float vf4 __attribute__((ext_vector_type(4)));

__device__ __forceinline__ float dot4(const float4 a, const float4 b) {
    return a.x * b.x + a.y * b.y + a.z * b.z + a.w * b.w;
}

__global__ __launch_bounds__(256, 2) void temp_attn_mega(
    const float* __restrict__ qI, const float* __restrict__ kI, const float* __restrict__ vI,
    const float* __restrict__ qT, const float* __restrict__ kT, const float* __restrict__ vT,
    float* __restrict__ out)
{
    // Intra strides: KST=68 (==4 mod 32 -> 4-way max, 1.58x), VST=64 (broadcast
    // reads, free), QST=68, SST=132 (rows 16B-aligned, conflict-free p4 reads).
    __shared__ __align__(16) float sKs[128 * 68];  // phase A: inter K(32x68)+V(32x64); phase B: intra K; then S(32x132)
    __shared__ __align__(16) float sVs[128 * 64];  // intra V
    __shared__ __align__(16) float sQs[32 * 68];   // intra Q tile
    __shared__ __align__(16) float sIO[8 * 68];    // inter out rows (8 x 64, stride 68)

    const int tid  = threadIdx.x;
    const int bid  = blockIdx.x;
    const int tile = bid & 3;
    const int h    = (bid >> 2) & 7;
    const int b    = bid >> 5;
    const int r0   = tile * 32;   // first intra row of this block
    const int pn0  = tile * 8;    // first inter row of this block

    // ================= Phase A: inter attention (8 rows) =================
    {
        const float* kg = kI + ((size_t)b * 32 * NH + h) * NE;
        const float* vg = vI + ((size_t)b * 32 * NH + h) * NE;
        float* dK = sKs;            // 32 rows, stride 68
        float* dV = sKs + 32 * 68;  // 32 rows, stride 64
        for (int idx = tid; idx < 32 * 16; idx += 256) {
            const int row = idx >> 4;
            const int f   = (idx & 15) * 4;
            *(float4*)&dK[row * 68 + f] = *(const float4*)(kg + (size_t)row * ROWSTRIDE + f);
            *(float4*)&dV[row * 64 + f] = *(const float4*)(vg + (size_t)row * ROWSTRIDE + f);
        }
    }
    __syncthreads();
    {
        const int rg = tid >> 5;     // 0..7: local inter row (pn0+rg)
        const int ln = tid & 31;     // key col / e-pair lane
        const float* dK = sKs;
        const float* dV = sKs + 32 * 68;

        // score[rg][ln] = (q . k) / 8 ; q row loads are wave-uniform (L2 broadcast)
        const float* qrow = qI + ((size_t)(b * 32 + pn0 + rg) * NH + h) * NE;
        float s = 0.f;
        #pragma unroll
        for (int e = 0; e < NE; e += 4) {
            const float4 qv = *(const float4*)(qrow + e);
            const float4 kv = *(const float4*)&dK[ln * 68 + e];
            s += dot4(qv, kv);
        }
        s *= 0.125f;
        // softmax across the 32 lanes of this half-wave
        float m = s;
        #pragma unroll
        for (int msk = 1; msk < 32; msk <<= 1) m = fmaxf(m, __shfl_xor(m, msk));
        const float p = __expf(s - m);
        float sum = p;
        #pragma unroll
        for (int msk = 1; msk < 32; msk <<= 1) sum += __shfl_xor(sum, msk);
        const float pn = p / sum;    // lane ln holds normalized p[col=ln] of row rg

        // PV: lane computes out[rg][2*ln .. 2*ln+1]; p broadcast via shfl
        const int hw = tid & 32;     // half-wave base within the 64-lane wave
        float o0 = 0.f, o1 = 0.f;
        #pragma unroll 8
        for (int c = 0; c < 32; c++) {
            const float pc = __shfl(pn, hw + c);
            const float2 v = *(const float2*)&dV[c * 64 + ln * 2];
            o0 += pc * v.x;
            o1 += pc * v.y;
        }
        sIO[rg * 68 + ln * 2]     = o0;
        sIO[rg * 68 + ln * 2 + 1] = o1;
    }
    __syncthreads();   // inter K/V dead; sIO complete

    // ================= Phase B: intra attention (32 rows) =================
    {
        const float* kg = kT + ((size_t)b * 128 * NH + h) * NE;
        const float* vg = vT + ((size_t)b * 128 * NH + h) * NE;
        const float* qg = qT + ((size_t)(b * 128 + r0) * NH + h) * NE;
        for (int idx = tid; idx < 128 * 16; idx += 256) {
            const int row = idx >> 4;
            const int f   = (idx & 15) * 4;
            *(float4*)&sKs[row * 68 + f] = *(const float4*)(kg + (size_t)row * ROWSTRIDE + f);
            *(float4*)&sVs[row * 64 + f] = *(const float4*)(vg + (size_t)row * ROWSTRIDE + f);
        }
        for (int idx = tid; idx < 32 * 16; idx += 256) {
            const int row = idx >> 4;
            const int f   = (idx & 15) * 4;
            *(float4*)&sQs[row * 68 + f] = *(const float4*)(qg + (size_t)row * ROWSTRIDE + f);
        }
    }
    __syncthreads();

    // scores in registers: thread (rg,cg) owns rows rg*4..+3, cols {cg+32j}
    const int rg = tid >> 5;
    const int cg = tid & 31;
    const int rr = rg * 4;
    float acc[4][4];
    #pragma unroll
    for (int i = 0; i < 4; i++)
        #pragma unroll
        for (int j = 0; j < 4; j++) acc[i][j] = 0.f;

    #pragma unroll
    for (int e = 0; e < NE; e += 4) {
        float4 qv[4], kv[4];
        #pragma unroll
        for (int i = 0; i < 4; i++) qv[i] = *(const float4*)&sQs[(rr + i) * 68 + e];
        #pragma unroll
        for (int j = 0; j < 4; j++) kv[j] = *(const float4*)&sKs[(cg + j * 32) * 68 + e];
        #pragma unroll
        for (int i = 0; i < 4; i++)
            #pragma unroll
            for (int j = 0; j < 4; j++)
                acc[i][j] += dot4(qv[i], kv[j]);
    }
    __syncthreads();               // all K reads done; Ks space is dead

    float* S = sKs;                // S: 32 rows x stride 132, aliased into Ks

    #pragma unroll
    for (int i = 0; i < 4; i++) {
        float m = acc[i][0] * 0.125f;
        #pragma unroll
        for (int j = 1; j < 4; j++) m = fmaxf(m, acc[i][j] * 0.125f);
        #pragma unroll
        for (int msk = 1; msk < 32; msk <<= 1) m = fmaxf(m, __shfl_xor(m, msk));
        float p[4], s = 0.f;
        #pragma unroll
        for (int j = 0; j < 4; j++) { p[j] = __expf(acc[i][j] * 0.125f - m); s += p[j]; }
        #pragma unroll
        for (int msk = 1; msk < 32; msk <<= 1) s += __shfl_xor(s, msk);
        const float inv = 1.f / s;
        #pragma unroll
        for (int j = 0; j < 4; j++)
            S[(rr + i) * 132 + cg + 32 * j] = p[j] * inv;
    }
    __syncthreads();

    // PV: thread (r, sub) computes V_intra[r][e0..e0+7]
    const int r   = tid >> 3;
    const int sub = tid & 7;
    const int e0  = sub * 8;
    float a0=0,a1=0,a2=0,a3=0,a4=0,a5=0,a6=0,a7=0;
    for (int c0 = 0; c0 < 128; c0 += 4) {
        const float4 p4 = *(const float4*)&S[r * 132 + c0];
        const float pv[4] = { p4.x, p4.y, p4.z, p4.w };
        #pragma unroll
        for (int u = 0; u < 4; u++) {
            const float p  = pv[u];
            const float4 va = *(const float4*)&sVs[(c0 + u) * 64 + e0];
            const float4 vb = *(const float4*)&sVs[(c0 + u) * 64 + e0 + 4];
            a0 += p * va.x; a1 += p * va.y; a2 += p * va.z; a3 += p * va.w;
            a4 += p * vb.x; a5 += p * vb.y; a6 += p * vb.z; a7 += p * vb.w;
        }
    }

    // ============ Epilogue: add inter row, duplicate-store 32 rows ============
    const int io = (r >> 2) * 68 + e0;          // local inter row = r>>2
    const float4 iA = *(const float4*)&sIO[io];
    const float4 iB = *(const float4*)&sIO[io + 4];
    vf4 oA, oB;
    oA.x = a0 + iA.x; oA.y = a1 + iA.y; oA.z = a2 + iA.z; oA.w = a3 + iA.w;
    oB.x = a4 + iB.x; oB.y = a5 + iB.y; oB.z = a6 + iB.z; oB.w = a7 + iB.w;

    const int i = r0 + r;                       // intra row 0..127
    float* ob = out + ((size_t)(b * 4096 + i * 32) * NH + h) * NE + e0;
    #pragma unroll
    for (int j = 0; j < 32; j++) {
        __builtin_nontemporal_store(oA, (vf4*)(ob + (size_t)j * ROWSTRIDE));
        __builtin_nontemporal_store(oB, (vf4*)(ob + (size_t)j * ROWSTRIDE + 4));
    }
}

extern "C" void kernel_launch(void* const* d_in, const int* in_sizes, int n_in,
                              void* d_out, int out_size, void* d_ws, size_t ws_size,
                              hipStream_t stream) {
    const float* q_inter = (const float*)d_in[0];
    const float* k_inter = (const float*)d_in[1];
    const float* v_inter = (const float*)d_in[2];
    const float* q_intra = (const float*)d_in[3];
    const float* k_intra = (const float*)d_in[4];
    const float* v_intra = (const float*)d_in[5];
    float* out = (float*)d_out;
    (void)d_ws; (void)ws_size;    // no workspace needed

    // One kernel: 512 blocks = (b, h, tile), 256 threads, 2 blocks/CU.
    temp_attn_mega<<<512, 256, 0, stream>>>(
        q_inter, k_inter, v_inter, q_intra, k_intra, v_intra, out);
}

// Round 6
// 178.022 us; speedup vs baseline: 1.1525x; 1.1525x over previous
//
#include <hip/hip_runtime.h>

// Problem: B=16, PATCH_NUM=32, PATCH_SIZE=128, H=8, E=64, WIN=4096
// out[b,l,h,e] = V_inter[b, l>>7, h, e] + V_intra[b, l>>5, h, e]
// V_* are full-softmax attentions (scale = 1/8) over L=32 / L=128.
//
// Round 5 -> 6:
//  * REVERT one-kernel duplicate-store (measured: 256B-comb scatter -> 2.6 TB/s,
//    82.7 us). Two kernels again: attention (compact) + h-spanning duplicate sweep.
//  * Attention kernel: 512 blocks (inter folded in, zero redundant work, no tail),
//    softmax AND P kept in registers (no S LDS round-trip), PV restructured:
//    lane owns one e-column, V read as fully-distinct ds_read_b32, P broadcast
//    via v_readlane (VALU) -> ~8x fewer LDS instructions than the broadcast-b128
//    PV that made attn ~37 us.
//  * Kernel 1 writes combined (intra + inter) rows -> kernel 2 is a pure
//    duplicator (4 MB read, 128 MB nontemporal write, 1 KB/instr contiguous).

#define NH 8
#define NE 64
#define ROWSTRIDE (NH * NE)   // 512 floats between consecutive l for fixed (b,h)

typedef float vf4 __attribute__((ext_vector_type(4)));

__device__ __forceinline__ float dot4(const float4 a, const float4 b) {
    return a.x * b.x + a.y * b.y + a.z * b.z + a.w * b.w;
}

__device__ __forceinline__ float readlane_f(float v, int lane) {
    return __uint_as_float(__builtin_amdgcn_readlane(__float_as_uint(v), lane));
}

// Block = (b, h, tile): inter rows [tile*8, tile*8+8) + intra rows
// [tile*32, tile*32+32); writes combined rows to wsSum[B,128,H,E] (4 MB).
__global__ __launch_bounds__(256, 2) void attn_combined(
    const float* __restrict__ qI, const float* __restrict__ kI, const float* __restrict__ vI,
    const float* __restrict__ qT, const float* __restrict__ kT, const float* __restrict__ vT,
    float* __restrict__ wsSum)
{
    // KST=68 (16B-aligned rows; 4-way max on b128 K reads = 1.58x, floor for
    // b128-aligned strides), VST=64 (PV reads distinct b32, conflict-free).
    __shared__ __align__(16) float sKs[128 * 68];  // phase A: inter K(32x68)+V(32x64); phase B: intra K
    __shared__ __align__(16) float sVs[128 * 64];  // intra V
    __shared__ __align__(16) float sQs[32 * 68];   // intra Q tile
    __shared__ __align__(16) float sIO[8 * 68];    // inter out rows (8 x 64, stride 68)

    const int tid  = threadIdx.x;
    const int bid  = blockIdx.x;
    const int tile = bid & 3;
    const int h    = (bid >> 2) & 7;
    const int b    = bid >> 5;
    const int r0   = tile * 32;   // first intra row of this block
    const int pn0  = tile * 8;    // first inter row of this block

    // ---- Stage: inter K,V into sKs region; intra V, intra Q (independent) ----
    {
        const float* kg = kI + ((size_t)b * 32 * NH + h) * NE;
        const float* vg = vI + ((size_t)b * 32 * NH + h) * NE;
        float* dK = sKs;            // 32 rows, stride 68
        float* dV = sKs + 32 * 68;  // 32 rows, stride 64
        for (int idx = tid; idx < 32 * 16; idx += 256) {
            const int row = idx >> 4;
            const int f   = (idx & 15) * 4;
            *(float4*)&dK[row * 68 + f] = *(const float4*)(kg + (size_t)row * ROWSTRIDE + f);
            *(float4*)&dV[row * 64 + f] = *(const float4*)(vg + (size_t)row * ROWSTRIDE + f);
        }
        const float* vgT = vT + ((size_t)b * 128 * NH + h) * NE;
        for (int idx = tid; idx < 128 * 16; idx += 256) {
            const int row = idx >> 4;
            const int f   = (idx & 15) * 4;
            *(float4*)&sVs[row * 64 + f] = *(const float4*)(vgT + (size_t)row * ROWSTRIDE + f);
        }
        const float* qgT = qT + ((size_t)(b * 128 + r0) * NH + h) * NE;
        for (int idx = tid; idx < 32 * 16; idx += 256) {
            const int row = idx >> 4;
            const int f   = (idx & 15) * 4;
            *(float4*)&sQs[row * 68 + f] = *(const float4*)(qgT + (size_t)row * ROWSTRIDE + f);
        }
    }
    __syncthreads();

    // ---- Phase A: inter attention (8 rows) -> sIO ----
    {
        const int rg = tid >> 5;     // 0..7: local inter row
        const int ln = tid & 31;
        const float* dK = sKs;
        const float* dV = sKs + 32 * 68;

        const float* qrow = qI + ((size_t)(b * 32 + pn0 + rg) * NH + h) * NE;
        float s = 0.f;
        #pragma unroll
        for (int e = 0; e < NE; e += 4) {
            const float4 qv = *(const float4*)(qrow + e);
            const float4 kv = *(const float4*)&dK[ln * 68 + e];
            s += dot4(qv, kv);
        }
        s *= 0.125f;
        float m = s;
        #pragma unroll
        for (int msk = 1; msk < 32; msk <<= 1) m = fmaxf(m, __shfl_xor(m, msk));
        const float pe = __expf(s - m);
        float sum = pe;
        #pragma unroll
        for (int msk = 1; msk < 32; msk <<= 1) sum += __shfl_xor(sum, msk);
        const float pn = pe / sum;

        const int hw = tid & 32;     // half-wave base
        float o0 = 0.f, o1 = 0.f;
        #pragma unroll 8
        for (int c = 0; c < 32; c++) {
            const float pc = __shfl(pn, hw + c);
            const float2 v = *(const float2*)&dV[c * 64 + ln * 2];
            o0 += pc * v.x;
            o1 += pc * v.y;
        }
        sIO[rg * 68 + ln * 2]     = o0;
        sIO[rg * 68 + ln * 2 + 1] = o1;
    }
    __syncthreads();   // inter K/V reads done; sKs free, sIO complete

    // ---- Stage intra K over sKs ----
    {
        const float* kgT = kT + ((size_t)b * 128 * NH + h) * NE;
        for (int idx = tid; idx < 128 * 16; idx += 256) {
            const int row = idx >> 4;
            const int f   = (idx & 15) * 4;
            *(float4*)&sKs[row * 68 + f] = *(const float4*)(kgT + (size_t)row * ROWSTRIDE + f);
        }
    }
    __syncthreads();

    // ---- Intra scores in registers: group (rg = tid>>5) rows rg*4..+3,
    //      lane cg owns cols {cg + 32j} ----
    const int rg = tid >> 5;
    const int cg = tid & 31;
    const int rr = rg * 4;
    float acc[4][4];
    #pragma unroll
    for (int i = 0; i < 4; i++)
        #pragma unroll
        for (int j = 0; j < 4; j++) acc[i][j] = 0.f;

    #pragma unroll
    for (int e = 0; e < NE; e += 4) {
        float4 qv[4], kv[4];
        #pragma unroll
        for (int i = 0; i < 4; i++) qv[i] = *(const float4*)&sQs[(rr + i) * 68 + e];
        #pragma unroll
        for (int j = 0; j < 4; j++) kv[j] = *(const float4*)&sKs[(cg + j * 32) * 68 + e];
        #pragma unroll
        for (int i = 0; i < 4; i++)
            #pragma unroll
            for (int j = 0; j < 4; j++)
                acc[i][j] += dot4(qv[i], kv[j]);
    }

    // ---- Softmax in registers -> normalized p[4][4] (no LDS round-trip) ----
    float p[4][4];
    #pragma unroll
    for (int i = 0; i < 4; i++) {
        float m = acc[i][0] * 0.125f;
        #pragma unroll
        for (int j = 1; j < 4; j++) m = fmaxf(m, acc[i][j] * 0.125f);
        #pragma unroll
        for (int msk = 1; msk < 32; msk <<= 1) m = fmaxf(m, __shfl_xor(m, msk));
        float s = 0.f;
        #pragma unroll
        for (int j = 0; j < 4; j++) { p[i][j] = __expf(acc[i][j] * 0.125f - m); s += p[i][j]; }
        #pragma unroll
        for (int msk = 1; msk < 32; msk <<= 1) s += __shfl_xor(s, msk);
        const float inv = 1.f / s;
        #pragma unroll
        for (int j = 0; j < 4; j++) p[i][j] *= inv;
    }

    // ---- PV: wave w owns rows 8w..8w+7; lane owns e-column = lane.
    //      V[c][lane]: distinct conflict-free ds_read_b32 (256 B/instr);
    //      p broadcast via v_readlane (VALU). No barrier needed: sVs/sIO
    //      were written before earlier barriers. ----
    const int lane = tid & 63;
    const int w    = tid >> 6;     // wave id: rows 8w..8w+7 (== groups 2w, 2w+1)
    float accE[8] = {0.f, 0.f, 0.f, 0.f, 0.f, 0.f, 0.f, 0.f};

    for (int j = 0; j < 4; j++) {          // c-chunk
        #pragma unroll
        for (int cc = 0; cc < 32; cc++) {
            const float v = sVs[(j * 32 + cc) * 64 + lane];
            #pragma unroll
            for (int i = 0; i < 8; i++) {
                // p of row (8w+i), col (32j+cc) lives in lane (i>>2)*32+cc, reg p[i&3][j]
                const float pc = readlane_f(p[i & 3][j], (i >> 2) * 32 + cc);
                accE[i] = fmaf(pc, v, accE[i]);
            }
        }
    }

    // ---- Epilogue: add inter row, write combined rows compactly ----
    #pragma unroll
    for (int i = 0; i < 8; i++) {
        const float vin = sIO[(2 * w + (i >> 2)) * 68 + lane];   // distinct b32
        const int   row = r0 + 8 * w + i;                         // intra row 0..127
        wsSum[((size_t)(b * 128 + row) * NH + h) * NE + lane] = accE[i] + vin;
    }
}

// Pure duplicator: out[b, pi*32+j, h, :] = wsSum[b, pi, h, :] for j in [0,32).
// Wave lanes span (h, e4) -> every store instruction is 1 KB contiguous.
__global__ __launch_bounds__(256) void duplicate_kernel(
    const float4* __restrict__ ws, float* __restrict__ out)
{
    const int t  = blockIdx.x * 256 + threadIdx.x;   // 0 .. 262143
    const int e4 = t & 15;
    const int h  = (t >> 4) & 7;
    const int pi = (t >> 7) & 127;
    const int b  = t >> 14;

    const float4 a = ws[((b * 128 + pi) * NH + h) * 16 + e4];
    vf4 s; s.x = a.x; s.y = a.y; s.z = a.z; s.w = a.w;

    float* o = out + ((((size_t)b * 4096 + pi * 32) * NH + h) * 16 + e4) * 4;
    #pragma unroll
    for (int j = 0; j < 32; j++)
        __builtin_nontemporal_store(s, (vf4*)(o + (size_t)j * ROWSTRIDE));
}

extern "C" void kernel_launch(void* const* d_in, const int* in_sizes, int n_in,
                              void* d_out, int out_size, void* d_ws, size_t ws_size,
                              hipStream_t stream) {
    const float* q_inter = (const float*)d_in[0];
    const float* k_inter = (const float*)d_in[1];
    const float* v_inter = (const float*)d_in[2];
    const float* q_intra = (const float*)d_in[3];
    const float* k_intra = (const float*)d_in[4];
    const float* v_intra = (const float*)d_in[5];
    float* out = (float*)d_out;
    float* ws  = (float*)d_ws;    // combined rows: [16,128,8,64] fp32 = 4 MiB

    // Attention (inter + intra + add) -> ws. 512 blocks = exactly 2/CU.
    attn_combined<<<512, 256, 0, stream>>>(
        q_inter, k_inter, v_inter, q_intra, k_intra, v_intra, ws);

    // Duplicate sweep -> out. 1024 blocks, 32 streaming stores/thread.
    duplicate_kernel<<<1024, 256, 0, stream>>>((const float4*)ws, out);
}

// Round 7
// 170.884 us; speedup vs baseline: 1.2006x; 1.0418x over previous
//
#include <hip/hip_runtime.h>

// Problem: B=16, PATCH_NUM=32, PATCH_SIZE=128, H=8, E=64, WIN=4096
// out[b,l,h,e] = V_inter[b, l>>7, h, e] + V_intra[b, l>>5, h, e]
// V_* are full-softmax attentions (scale = 1/8) over L=32 / L=128.
//
// Round 6 -> 7: intra attention moved to MFMA (bf16 in, fp32 acc).
// Back-solve showed attn_combined ~30 us: LDS-pipe (~9.5 us/CU) + VALU issue
// (~6 us) bound at 2 waves/SIMD. MFMA replaces 2048 FMA + ~450 LDS instr per
// thread with 16 MFMA + ~40 b128 frag reads per wave.
// Layout facts (HW-verified per guide): C/D col=lane&15, row=quad*4+reg;
// A/B frags read 8 contiguous k-elems from row-major [m][k]/[n][k] (B^T
// pattern); P needs LDS round-trip between QK^T and PV.

#define NH 8
#define NE 64
#define ROWSTRIDE 512   // floats between consecutive l for fixed (b,h)

typedef float  vf4 __attribute__((ext_vector_type(4)));
typedef short  v8s __attribute__((ext_vector_type(8)));

__device__ __forceinline__ float dot4(const float4 a, const float4 b) {
    return a.x * b.x + a.y * b.y + a.z * b.z + a.w * b.w;
}

__device__ __forceinline__ unsigned short f2bf(float f) {   // RNE fp32->bf16
    unsigned int u = __float_as_uint(f);
    u += 0x7fff + ((u >> 16) & 1);
    return (unsigned short)(u >> 16);
}

// ---------------- LDS map (bytes), phase-aliased ----------------
// region1 [0, 23040):     sKb bf16[128][72] (18432) | sQb bf16[32][72] (4608)
//                         alias after scores: sS fp32[32][132] (16896)
// region2 [23040, 49152): sVb bf16[64][136]=V^T (17408) | sP bf16[32][136] (8704)
//                         alias before intra-V staged: interK f32[32][68] (8704)
//                                                    + interV f32[32][64] (8192)
// sIO     [49152, 51328): fp32[8][68] inter-out rows
#define SMEM_BYTES 51328
#define OFF_QB  18432
#define OFF_R2  23040
#define OFF_IV  31744
#define OFF_P   40448
#define OFF_IO  49152

// Block = (b, h, tile): inter rows [tile*8,+8) + intra rows [tile*32,+32);
// writes combined rows to wsSum[B,128,H,E] (4 MB).
__global__ __launch_bounds__(256, 2) void attn_mfma(
    const float* __restrict__ qI, const float* __restrict__ kI, const float* __restrict__ vI,
    const float* __restrict__ qT, const float* __restrict__ kT, const float* __restrict__ vT,
    float* __restrict__ wsSum)
{
    __shared__ __align__(16) char smem[SMEM_BYTES];

    const int tid  = threadIdx.x;
    const int bid  = blockIdx.x;
    const int tile = bid & 3;
    const int h    = (bid >> 2) & 7;
    const int b    = bid >> 5;
    const int r0   = tile * 32;   // first intra row
    const int pn0  = tile * 8;    // first inter row

    // ---- 1. stage inter K,V (fp32) into region2 ----
    {
        const float* kg = kI + ((size_t)b * 32 * NH + h) * NE;
        const float* vg = vI + ((size_t)b * 32 * NH + h) * NE;
        float* dK = (float*)(smem + OFF_R2);   // [32][68]
        float* dV = (float*)(smem + OFF_IV);   // [32][64]
        for (int idx = tid; idx < 32 * 16; idx += 256) {
            const int row = idx >> 4;
            const int f   = (idx & 15) * 4;
            *(float4*)&dK[row * 68 + f] = *(const float4*)(kg + (size_t)row * ROWSTRIDE + f);
            *(float4*)&dV[row * 64 + f] = *(const float4*)(vg + (size_t)row * ROWSTRIDE + f);
        }
    }
    __syncthreads();

    // ---- 2a. stage intra K,Q as bf16 into region1 (independent of phase A) ----
    {
        const float* kgT = kT + ((size_t)b * 128 * NH + h) * NE;
        unsigned short* wKb = (unsigned short*)smem;            // [128][72]
        for (int idx = tid; idx < 128 * 16; idx += 256) {
            const int row = idx >> 4;
            const int f   = (idx & 15) * 4;
            const float4 v = *(const float4*)(kgT + (size_t)row * ROWSTRIDE + f);
            ushort4 pk; pk.x = f2bf(v.x); pk.y = f2bf(v.y); pk.z = f2bf(v.z); pk.w = f2bf(v.w);
            *(ushort4*)(wKb + row * 72 + f) = pk;
        }
        const float* qgT = qT + ((size_t)(b * 128 + r0) * NH + h) * NE;
        unsigned short* wQb = (unsigned short*)(smem + OFF_QB); // [32][72]
        for (int idx = tid; idx < 32 * 16; idx += 256) {
            const int row = idx >> 4;
            const int f   = (idx & 15) * 4;
            const float4 v = *(const float4*)(qgT + (size_t)row * ROWSTRIDE + f);
            ushort4 pk; pk.x = f2bf(v.x); pk.y = f2bf(v.y); pk.z = f2bf(v.z); pk.w = f2bf(v.w);
            *(ushort4*)(wQb + row * 72 + f) = pk;
        }
    }

    // ---- 2b. phase A: inter attention (8 rows, fp32 VALU) -> sIO ----
    {
        const int rg = tid >> 5;     // 0..7: local inter row
        const int ln = tid & 31;
        const float* dK  = (const float*)(smem + OFF_R2);
        const float* dV  = (const float*)(smem + OFF_IV);
        float*       sIO = (float*)(smem + OFF_IO);

        const float* qrow = qI + ((size_t)(b * 32 + pn0 + rg) * NH + h) * NE;
        float s = 0.f;
        #pragma unroll
        for (int e = 0; e < NE; e += 4) {
            const float4 qv = *(const float4*)(qrow + e);
            const float4 kv = *(const float4*)&dK[ln * 68 + e];
            s += dot4(qv, kv);
        }
        s *= 0.125f;
        float m = s;
        #pragma unroll
        for (int msk = 1; msk < 32; msk <<= 1) m = fmaxf(m, __shfl_xor(m, msk));
        const float pe = __expf(s - m);
        float sum = pe;
        #pragma unroll
        for (int msk = 1; msk < 32; msk <<= 1) sum += __shfl_xor(sum, msk);
        const float pn = pe / sum;

        const int hw = tid & 32;     // half-wave base within the 64-lane wave
        float o0 = 0.f, o1 = 0.f;
        #pragma unroll 8
        for (int c = 0; c < 32; c++) {
            const float pc = __shfl(pn, hw + c);
            const float2 v = *(const float2*)&dV[c * 64 + ln * 2];
            o0 += pc * v.x;
            o1 += pc * v.y;
        }
        sIO[rg * 68 + ln * 2]     = o0;
        sIO[rg * 68 + ln * 2 + 1] = o1;
    }
    __syncthreads();   // phase A done reading region2; region1 staged

    // ---- 3. stage intra V transposed (bf16 V^T[e][c]) over region2 ----
    {
        const float* vgT = vT + ((size_t)b * 128 * NH + h) * NE;
        unsigned short* wVb = (unsigned short*)(smem + OFF_R2);  // [64][136]
        for (int idx = tid; idx < 128 * 16; idx += 256) {
            const int c = idx >> 4;
            const int f = (idx & 15) * 4;
            const float4 v = *(const float4*)(vgT + (size_t)c * ROWSTRIDE + f);
            const float arr[4] = { v.x, v.y, v.z, v.w };
            #pragma unroll
            for (int i = 0; i < 4; i++) {
                const int j = (c + i) & 3;          // rotate to spread banks
                wVb[(f + j) * 136 + c] = f2bf(arr[j]);
            }
        }
    }
    __syncthreads();

    // ---- 4. MFMA scores: D(32x128) = Q(32x64) . K^T(64x128) ----
    const int lane = tid & 63;
    const int ln15 = lane & 15;
    const int quad = lane >> 4;
    const int w    = tid >> 6;      // wave 0..3
    const int mt   = w & 1;         // M-tile (16 q-rows)
    const int ntb  = (w >> 1) * 4;  // first of 4 N-tiles (16 kv-rows each)

    vf4 accS[4];
    #pragma unroll
    for (int t = 0; t < 4; t++) accS[t] = (vf4){0.f, 0.f, 0.f, 0.f};
    {
        const unsigned short* sKb = (const unsigned short*)smem;
        const unsigned short* sQb = (const unsigned short*)(smem + OFF_QB);
        #pragma unroll
        for (int kt = 0; kt < 2; kt++) {
            const v8s aQ = *(const v8s*)(sQb + (mt * 16 + ln15) * 72 + kt * 32 + quad * 8);
            #pragma unroll
            for (int t = 0; t < 4; t++) {
                const v8s bK = *(const v8s*)(sKb + ((ntb + t) * 16 + ln15) * 72 + kt * 32 + quad * 8);
                accS[t] = __builtin_amdgcn_mfma_f32_16x16x32_bf16(aQ, bK, accS[t], 0, 0, 0);
            }
        }
    }
    __syncthreads();   // all frag reads done; region1 dead -> becomes sS

    // ---- 5. write scaled scores to sS fp32[32][132] (C-layout scatter) ----
    {
        float* sS = (float*)smem;
        #pragma unroll
        for (int t = 0; t < 4; t++)
            #pragma unroll
            for (int reg = 0; reg < 4; reg++)
                sS[(mt * 16 + quad * 4 + reg) * 132 + (ntb + t) * 16 + ln15]
                    = accS[t][reg] * 0.125f;
    }
    __syncthreads();

    // ---- 6. softmax (fp32) -> normalized P bf16[32][136] ----
    {
        const float* sS = (const float*)smem;
        unsigned short* sP = (unsigned short*)(smem + OFF_P);
        const int r   = tid >> 3;
        const int sub = tid & 7;
        float vals[16];
        const float* Srow = sS + r * 132 + sub * 16;
        #pragma unroll
        for (int c4 = 0; c4 < 4; c4++) {
            const float4 v = *(const float4*)(Srow + c4 * 4);
            vals[c4*4+0] = v.x; vals[c4*4+1] = v.y; vals[c4*4+2] = v.z; vals[c4*4+3] = v.w;
        }
        float m = vals[0];
        #pragma unroll
        for (int i = 1; i < 16; i++) m = fmaxf(m, vals[i]);
        #pragma unroll
        for (int msk = 1; msk < 8; msk <<= 1) m = fmaxf(m, __shfl_xor(m, msk));
        float s = 0.f;
        #pragma unroll
        for (int i = 0; i < 16; i++) { vals[i] = __expf(vals[i] - m); s += vals[i]; }
        #pragma unroll
        for (int msk = 1; msk < 8; msk <<= 1) s += __shfl_xor(s, msk);
        const float inv = 1.f / s;
        #pragma unroll
        for (int c4 = 0; c4 < 4; c4++) {
            ushort4 pk;
            pk.x = f2bf(vals[c4*4+0] * inv); pk.y = f2bf(vals[c4*4+1] * inv);
            pk.z = f2bf(vals[c4*4+2] * inv); pk.w = f2bf(vals[c4*4+3] * inv);
            *(ushort4*)(sP + r * 136 + sub * 16 + c4 * 4) = pk;
        }
    }
    __syncthreads();

    // ---- 7. MFMA PV: O(32x64) = P(32x128) . V(128x64), + inter add ----
    {
        const unsigned short* sVb = (const unsigned short*)(smem + OFF_R2);
        const unsigned short* sP  = (const unsigned short*)(smem + OFF_P);
        const float*          sIO = (const float*)(smem + OFF_IO);
        const int neb = (w >> 1) * 2;   // first of 2 N-tiles (16 e each)

        vf4 accO[2];
        accO[0] = (vf4){0.f, 0.f, 0.f, 0.f};
        accO[1] = (vf4){0.f, 0.f, 0.f, 0.f};
        #pragma unroll
        for (int kt = 0; kt < 4; kt++) {
            const v8s aP = *(const v8s*)(sP + (mt * 16 + ln15) * 136 + kt * 32 + quad * 8);
            #pragma unroll
            for (int t = 0; t < 2; t++) {
                const v8s bV = *(const v8s*)(sVb + ((neb + t) * 16 + ln15) * 136 + kt * 32 + quad * 8);
                accO[t] = __builtin_amdgcn_mfma_f32_16x16x32_bf16(aP, bV, accO[t], 0, 0, 0);
            }
        }

        #pragma unroll
        for (int t = 0; t < 2; t++) {
            const int e   = (neb + t) * 16 + ln15;
            const float vin = sIO[(mt * 4 + quad) * 68 + e];   // inter row = (introw>>2)
            #pragma unroll
            for (int reg = 0; reg < 4; reg++) {
                const int row = r0 + mt * 16 + quad * 4 + reg;
                wsSum[((size_t)(b * 128 + row) * NH + h) * NE + e] = accO[t][reg] + vin;
            }
        }
    }
}

// Pure duplicator: out[b, pi*32+j, h, :] = wsSum[b, pi, h, :] for j in [0,32).
// Wave lanes span (h, e4) -> every store instruction is 1 KB contiguous.
__global__ __launch_bounds__(256) void duplicate_kernel(
    const float4* __restrict__ ws, float* __restrict__ out)
{
    const int t  = blockIdx.x * 256 + threadIdx.x;   // 0 .. 262143
    const int e4 = t & 15;
    const int h  = (t >> 4) & 7;
    const int pi = (t >> 7) & 127;
    const int b  = t >> 14;

    const float4 a = ws[((b * 128 + pi) * NH + h) * 16 + e4];
    vf4 s; s.x = a.x; s.y = a.y; s.z = a.z; s.w = a.w;

    float* o = out + ((((size_t)b * 4096 + pi * 32) * NH + h) * 16 + e4) * 4;
    #pragma unroll
    for (int j = 0; j < 32; j++)
        __builtin_nontemporal_store(s, (vf4*)(o + (size_t)j * ROWSTRIDE));
}

extern "C" void kernel_launch(void* const* d_in, const int* in_sizes, int n_in,
                              void* d_out, int out_size, void* d_ws, size_t ws_size,
                              hipStream_t stream) {
    const float* q_inter = (const float*)d_in[0];
    const float* k_inter = (const float*)d_in[1];
    const float* v_inter = (const float*)d_in[2];
    const float* q_intra = (const float*)d_in[3];
    const float* k_intra = (const float*)d_in[4];
    const float* v_intra = (const float*)d_in[5];
    float* out = (float*)d_out;
    float* ws  = (float*)d_ws;    // combined rows: [16,128,8,64] fp32 = 4 MiB

    // Attention (inter fp32 + intra MFMA-bf16 + add) -> ws. 512 blocks, 2/CU.
    attn_mfma<<<512, 256, 0, stream>>>(
        q_inter, k_inter, v_inter, q_intra, k_intra, v_intra, ws);

    // Duplicate sweep -> out. 1024 blocks, 32 streaming stores/thread.
    duplicate_kernel<<<1024, 256, 0, stream>>>((const float4*)ws, out);
}

// Round 8
// 170.163 us; speedup vs baseline: 1.2057x; 1.0042x over previous
//
#include <hip/hip_runtime.h>

// Problem: B=16, PATCH_NUM=32, PATCH_SIZE=128, H=8, E=64, WIN=4096
// out[b,l,h,e] = V_inter[b, l>>7, h, e] + V_intra[b, l>>5, h, e]
// V_* are full-softmax attentions (scale = 1/8) over L=32 / L=128.
//
// Round 7 -> 8: de-serialize. attn_mfma measured ~24 us: 6 barriers at
// 2 blocks/CU with the fp32 inter branch in series. Now:
//  * heterogeneous grid 640: blocks 0-127 = inter (one (b,h) each, fp32
//    VALU) -> wsI; blocks 128-639 = intra MFMA only -> wsT. Inter add moved
//    to the duplicate kernel (1 extra L2 read, free).
//  * intra path: 4 barriers (stage | QK-mfma | S-scatter | softmax->P | PV).
//  * LDS 48.0 KB, __launch_bounds__(256,3) -> 3 blocks/CU; all 640 blocks
//    co-resident, ~10 waves/CU.

#define NH 8
#define NE 64
#define ROWSTRIDE 512   // floats between consecutive l for fixed (b,h)

typedef float  vf4 __attribute__((ext_vector_type(4)));
typedef short  v8s __attribute__((ext_vector_type(8)));

__device__ __forceinline__ float dot4(const float4 a, const float4 b) {
    return a.x * b.x + a.y * b.y + a.z * b.z + a.w * b.w;
}

__device__ __forceinline__ unsigned short f2bf(float f) {   // RNE fp32->bf16
    unsigned int u = __float_as_uint(f);
    u += 0x7fff + ((u >> 16) & 1);
    return (unsigned short)(u >> 16);
}

// ---------------- LDS map (bytes), intra path ----------------
// region1 [0, 23040):  sKb bf16[128][72] | sQb bf16[32][72] @18432
//                      alias after QK frag reads: sS fp32[32][132] (16896)
// region2 [23040, 49152): sVb bf16[64][136] = V^T | sP bf16[32][136] @40448
// Inter blocks reuse [0, 16896): dK f32[32][68] | dV f32[32][64] @8704
#define SMEM_BYTES 49152
#define OFF_QB  18432
#define OFF_VB  23040
#define OFF_P   40448

__global__ __launch_bounds__(256, 3) void attn_split(
    const float* __restrict__ qI, const float* __restrict__ kI, const float* __restrict__ vI,
    const float* __restrict__ qT, const float* __restrict__ kT, const float* __restrict__ vT,
    float* __restrict__ wsT, float* __restrict__ wsI)
{
    __shared__ __align__(16) char smem[SMEM_BYTES];
    const int tid = threadIdx.x;
    const int bid = blockIdx.x;

    if (bid < 128) {
        // ================= INTER block: one (b,h), 32 rows x 32 cols =========
        const int b = bid >> 3;
        const int h = bid & 7;
        float* dK = (float*)smem;            // [32][68]
        float* dV = (float*)(smem + 8704);   // [32][64]
        {
            const float* kg = kI + ((size_t)b * 32 * NH + h) * NE;
            const float* vg = vI + ((size_t)b * 32 * NH + h) * NE;
            for (int idx = tid; idx < 32 * 16; idx += 256) {
                const int row = idx >> 4;
                const int f   = (idx & 15) * 4;
                *(float4*)&dK[row * 68 + f] = *(const float4*)(kg + (size_t)row * ROWSTRIDE + f);
                *(float4*)&dV[row * 64 + f] = *(const float4*)(vg + (size_t)row * ROWSTRIDE + f);
            }
        }
        __syncthreads();

        const int rg = tid >> 5;     // 0..7
        const int ln = tid & 31;
        const int hw = tid & 32;     // half-wave base
        #pragma unroll
        for (int it = 0; it < 4; it++) {
            const int row = it * 8 + rg;
            const float* qrow = qI + ((size_t)(b * 32 + row) * NH + h) * NE;
            float s = 0.f;
            #pragma unroll
            for (int e = 0; e < NE; e += 4) {
                const float4 qv = *(const float4*)(qrow + e);
                const float4 kv = *(const float4*)&dK[ln * 68 + e];
                s += dot4(qv, kv);
            }
            s *= 0.125f;
            float m = s;
            #pragma unroll
            for (int msk = 1; msk < 32; msk <<= 1) m = fmaxf(m, __shfl_xor(m, msk));
            const float pe = __expf(s - m);
            float sum = pe;
            #pragma unroll
            for (int msk = 1; msk < 32; msk <<= 1) sum += __shfl_xor(sum, msk);
            const float pn = pe / sum;

            float o0 = 0.f, o1 = 0.f;
            #pragma unroll 8
            for (int c = 0; c < 32; c++) {
                const float pc = __shfl(pn, hw + c);
                const float2 v = *(const float2*)&dV[c * 64 + ln * 2];
                o0 += pc * v.x;
                o1 += pc * v.y;
            }
            float2 o2; o2.x = o0; o2.y = o1;
            *(float2*)(wsI + ((size_t)(b * 32 + row) * NH + h) * NE + ln * 2) = o2;
        }
        return;
    }

    // ================= INTRA block: (b, h, tile-of-32-rows), MFMA ===========
    const int ib   = bid - 128;
    const int tile = ib & 3;
    const int h    = (ib >> 2) & 7;
    const int b    = ib >> 5;
    const int r0   = tile * 32;

    // ---- 1. stage intra K,Q (bf16 row-major) and V^T (bf16), one barrier ----
    {
        const float* kg = kT + ((size_t)b * 128 * NH + h) * NE;
        unsigned short* wKb = (unsigned short*)smem;            // [128][72]
        for (int idx = tid; idx < 128 * 16; idx += 256) {
            const int row = idx >> 4;
            const int f   = (idx & 15) * 4;
            const float4 v = *(const float4*)(kg + (size_t)row * ROWSTRIDE + f);
            ushort4 pk; pk.x = f2bf(v.x); pk.y = f2bf(v.y); pk.z = f2bf(v.z); pk.w = f2bf(v.w);
            *(ushort4*)(wKb + row * 72 + f) = pk;
        }
        const float* qg = qT + ((size_t)(b * 128 + r0) * NH + h) * NE;
        unsigned short* wQb = (unsigned short*)(smem + OFF_QB); // [32][72]
        for (int idx = tid; idx < 32 * 16; idx += 256) {
            const int row = idx >> 4;
            const int f   = (idx & 15) * 4;
            const float4 v = *(const float4*)(qg + (size_t)row * ROWSTRIDE + f);
            ushort4 pk; pk.x = f2bf(v.x); pk.y = f2bf(v.y); pk.z = f2bf(v.z); pk.w = f2bf(v.w);
            *(ushort4*)(wQb + row * 72 + f) = pk;
        }
        const float* vg = vT + ((size_t)b * 128 * NH + h) * NE;
        unsigned short* wVb = (unsigned short*)(smem + OFF_VB); // [64][136] = V^T
        for (int idx = tid; idx < 128 * 16; idx += 256) {
            const int c = idx >> 4;
            const int f = (idx & 15) * 4;
            const float4 v = *(const float4*)(vg + (size_t)c * ROWSTRIDE + f);
            const float arr[4] = { v.x, v.y, v.z, v.w };
            #pragma unroll
            for (int i = 0; i < 4; i++) {
                const int j = (c + i) & 3;          // rotate to spread banks
                wVb[(f + j) * 136 + c] = f2bf(arr[j]);
            }
        }
    }
    __syncthreads();

    // ---- 2. MFMA scores: D(32x128) = Q(32x64) . K^T(64x128) ----
    const int lane = tid & 63;
    const int ln15 = lane & 15;
    const int quad = lane >> 4;
    const int w    = tid >> 6;      // wave 0..3
    const int mt   = w & 1;         // M-tile (16 q-rows)
    const int ntb  = (w >> 1) * 4;  // first of 4 N-tiles (16 kv-rows each)

    vf4 accS[4];
    #pragma unroll
    for (int t = 0; t < 4; t++) accS[t] = (vf4){0.f, 0.f, 0.f, 0.f};
    {
        const unsigned short* sKb = (const unsigned short*)smem;
        const unsigned short* sQb = (const unsigned short*)(smem + OFF_QB);
        #pragma unroll
        for (int kt = 0; kt < 2; kt++) {
            const v8s aQ = *(const v8s*)(sQb + (mt * 16 + ln15) * 72 + kt * 32 + quad * 8);
            #pragma unroll
            for (int t = 0; t < 4; t++) {
                const v8s bK = *(const v8s*)(sKb + ((ntb + t) * 16 + ln15) * 72 + kt * 32 + quad * 8);
                accS[t] = __builtin_amdgcn_mfma_f32_16x16x32_bf16(aQ, bK, accS[t], 0, 0, 0);
            }
        }
    }
    __syncthreads();   // all frag reads done; region1 dead -> becomes sS

    // ---- 3. scatter scaled scores to sS fp32[32][132] (C-layout) ----
    {
        float* sS = (float*)smem;
        #pragma unroll
        for (int t = 0; t < 4; t++)
            #pragma unroll
            for (int reg = 0; reg < 4; reg++)
                sS[(mt * 16 + quad * 4 + reg) * 132 + (ntb + t) * 16 + ln15]
                    = accS[t][reg] * 0.125f;
    }
    __syncthreads();

    // ---- 4. softmax (fp32) -> normalized P bf16[32][136] ----
    {
        const float* sS = (const float*)smem;
        unsigned short* sP = (unsigned short*)(smem + OFF_P);
        const int r   = tid >> 3;
        const int sub = tid & 7;
        float vals[16];
        const float* Srow = sS + r * 132 + sub * 16;
        #pragma unroll
        for (int c4 = 0; c4 < 4; c4++) {
            const float4 v = *(const float4*)(Srow + c4 * 4);
            vals[c4*4+0] = v.x; vals[c4*4+1] = v.y; vals[c4*4+2] = v.z; vals[c4*4+3] = v.w;
        }
        float m = vals[0];
        #pragma unroll
        for (int i = 1; i < 16; i++) m = fmaxf(m, vals[i]);
        #pragma unroll
        for (int msk = 1; msk < 8; msk <<= 1) m = fmaxf(m, __shfl_xor(m, msk));
        float s = 0.f;
        #pragma unroll
        for (int i = 0; i < 16; i++) { vals[i] = __expf(vals[i] - m); s += vals[i]; }
        #pragma unroll
        for (int msk = 1; msk < 8; msk <<= 1) s += __shfl_xor(s, msk);
        const float inv = 1.f / s;
        #pragma unroll
        for (int c4 = 0; c4 < 4; c4++) {
            ushort4 pk;
            pk.x = f2bf(vals[c4*4+0] * inv); pk.y = f2bf(vals[c4*4+1] * inv);
            pk.z = f2bf(vals[c4*4+2] * inv); pk.w = f2bf(vals[c4*4+3] * inv);
            *(ushort4*)(sP + r * 136 + sub * 16 + c4 * 4) = pk;
        }
    }
    __syncthreads();

    // ---- 5. MFMA PV: O(32x64) = P(32x128) . V(128x64) -> wsT ----
    {
        const unsigned short* sVb = (const unsigned short*)(smem + OFF_VB);
        const unsigned short* sP  = (const unsigned short*)(smem + OFF_P);
        const int neb = (w >> 1) * 2;   // first of 2 N-tiles (16 e each)

        vf4 accO[2];
        accO[0] = (vf4){0.f, 0.f, 0.f, 0.f};
        accO[1] = (vf4){0.f, 0.f, 0.f, 0.f};
        #pragma unroll
        for (int kt = 0; kt < 4; kt++) {
            const v8s aP = *(const v8s*)(sP + (mt * 16 + ln15) * 136 + kt * 32 + quad * 8);
            #pragma unroll
            for (int t = 0; t < 2; t++) {
                const v8s bV = *(const v8s*)(sVb + ((neb + t) * 16 + ln15) * 136 + kt * 32 + quad * 8);
                accO[t] = __builtin_amdgcn_mfma_f32_16x16x32_bf16(aP, bV, accO[t], 0, 0, 0);
            }
        }
        #pragma unroll
        for (int t = 0; t < 2; t++) {
            const int e = (neb + t) * 16 + ln15;
            #pragma unroll
            for (int reg = 0; reg < 4; reg++) {
                const int row = r0 + mt * 16 + quad * 4 + reg;
                wsT[((size_t)(b * 128 + row) * NH + h) * NE + e] = accO[t][reg];
            }
        }
    }
}

// out[b, pi*32+j, h, :] = wsT[b, pi, h, :] + wsI[b, pi>>2, h, :], j in [0,32).
// Wave lanes span (h, e4) -> every store instruction is 1 KB contiguous.
__global__ __launch_bounds__(256) void duplicate_add_kernel(
    const float4* __restrict__ wsT, const float4* __restrict__ wsI,
    float* __restrict__ out)
{
    const int t  = blockIdx.x * 256 + threadIdx.x;   // 0 .. 262143
    const int e4 = t & 15;
    const int h  = (t >> 4) & 7;
    const int pi = (t >> 7) & 127;
    const int b  = t >> 14;

    const float4 a = wsT[((b * 128 + pi) * NH + h) * 16 + e4];
    const float4 c = wsI[((b * 32 + (pi >> 2)) * NH + h) * 16 + e4];
    vf4 s; s.x = a.x + c.x; s.y = a.y + c.y; s.z = a.z + c.z; s.w = a.w + c.w;

    float* o = out + ((((size_t)b * 4096 + pi * 32) * NH + h) * 16 + e4) * 4;
    #pragma unroll
    for (int j = 0; j < 32; j++)
        __builtin_nontemporal_store(s, (vf4*)(o + (size_t)j * ROWSTRIDE));
}

extern "C" void kernel_launch(void* const* d_in, const int* in_sizes, int n_in,
                              void* d_out, int out_size, void* d_ws, size_t ws_size,
                              hipStream_t stream) {
    const float* q_inter = (const float*)d_in[0];
    const float* k_inter = (const float*)d_in[1];
    const float* v_inter = (const float*)d_in[2];
    const float* q_intra = (const float*)d_in[3];
    const float* k_intra = (const float*)d_in[4];
    const float* v_intra = (const float*)d_in[5];
    float* out = (float*)d_out;
    float* wsT = (float*)d_ws;                        // V_intra: [16,128,8,64] = 4 MiB
    float* wsI = wsT + (size_t)16 * 128 * NH * NE;    // V_inter: [16,32,8,64]  = 1 MiB

    // Heterogeneous grid: 128 inter blocks + 512 intra blocks, all co-resident.
    attn_split<<<640, 256, 0, stream>>>(
        q_inter, k_inter, v_inter, q_intra, k_intra, v_intra, wsT, wsI);

    // Duplicate + add sweep -> out. 1024 blocks, 32 streaming stores/thread.
    duplicate_add_kernel<<<1024, 256, 0, stream>>>(
        (const float4*)wsT, (const float4*)wsI, out);
}

// Round 9
// 166.822 us; speedup vs baseline: 1.2298x; 1.0200x over previous
//
#include <hip/hip_runtime.h>

// Problem: B=16, PATCH_NUM=32, PATCH_SIZE=128, H=8, E=64, WIN=4096
// out[b,l,h,e] = V_inter[b, l>>7, h, e] + V_intra[b, l>>5, h, e]
// V_* are full-softmax attentions (scale = 1/8) over L=32 / L=128.
//
// Round 8 -> 9: staging MLP fix. R8 showed barriers/occupancy weren't the
// limit; the staging loops were latency-bound (load->convert->ds_write dep
// chain = ~2 loads in flight/wave -> ~1.2 TB/s effective -> ~13 us).
// Now: issue ALL 18 float4 global loads back-to-back into registers, then
// convert+store. ~3.5 KB/CU in flight covers L2-hit latency -> staging ~3 us.

#define NH 8
#define NE 64
#define ROWSTRIDE 512   // floats between consecutive l for fixed (b,h)

typedef float  vf4 __attribute__((ext_vector_type(4)));
typedef short  v8s __attribute__((ext_vector_type(8)));

__device__ __forceinline__ float dot4(const float4 a, const float4 b) {
    return a.x * b.x + a.y * b.y + a.z * b.z + a.w * b.w;
}

__device__ __forceinline__ unsigned short f2bf(float f) {   // RNE fp32->bf16
    unsigned int u = __float_as_uint(f);
    u += 0x7fff + ((u >> 16) & 1);
    return (unsigned short)(u >> 16);
}

// ---------------- LDS map (bytes), intra path ----------------
// region1 [0, 23040):  sKb bf16[128][72] | sQb bf16[32][72] @18432
//                      alias after QK frag reads: sS fp32[32][132] (16896)
// region2 [23040, 49152): sVb bf16[64][136] = V^T | sP bf16[32][136] @40448
// Inter blocks reuse [0, 16896): dK f32[32][68] | dV f32[32][64] @8704
#define SMEM_BYTES 49152
#define OFF_QB  18432
#define OFF_VB  23040
#define OFF_P   40448

__global__ __launch_bounds__(256, 3) void attn_split(
    const float* __restrict__ qI, const float* __restrict__ kI, const float* __restrict__ vI,
    const float* __restrict__ qT, const float* __restrict__ kT, const float* __restrict__ vT,
    float* __restrict__ wsT, float* __restrict__ wsI)
{
    __shared__ __align__(16) char smem[SMEM_BYTES];
    const int tid = threadIdx.x;
    const int bid = blockIdx.x;

    if (bid < 128) {
        // ================= INTER block: one (b,h), 32 rows x 32 cols =========
        const int b = bid >> 3;
        const int h = bid & 7;
        float* dK = (float*)smem;            // [32][68]
        float* dV = (float*)(smem + 8704);   // [32][64]
        {
            const float* kg = kI + ((size_t)b * 32 * NH + h) * NE;
            const float* vg = vI + ((size_t)b * 32 * NH + h) * NE;
            float4 kr[2], vr[2];
            #pragma unroll
            for (int i = 0; i < 2; i++) {
                const int idx = tid + i * 256;
                const int row = idx >> 4, f = (idx & 15) * 4;
                kr[i] = *(const float4*)(kg + (size_t)row * ROWSTRIDE + f);
                vr[i] = *(const float4*)(vg + (size_t)row * ROWSTRIDE + f);
            }
            #pragma unroll
            for (int i = 0; i < 2; i++) {
                const int idx = tid + i * 256;
                const int row = idx >> 4, f = (idx & 15) * 4;
                *(float4*)&dK[row * 68 + f] = kr[i];
                *(float4*)&dV[row * 64 + f] = vr[i];
            }
        }
        __syncthreads();

        const int rg = tid >> 5;     // 0..7
        const int ln = tid & 31;
        const int hw = tid & 32;     // half-wave base
        #pragma unroll
        for (int it = 0; it < 4; it++) {
            const int row = it * 8 + rg;
            const float* qrow = qI + ((size_t)(b * 32 + row) * NH + h) * NE;
            float s = 0.f;
            #pragma unroll
            for (int e = 0; e < NE; e += 4) {
                const float4 qv = *(const float4*)(qrow + e);
                const float4 kv = *(const float4*)&dK[ln * 68 + e];
                s += dot4(qv, kv);
            }
            s *= 0.125f;
            float m = s;
            #pragma unroll
            for (int msk = 1; msk < 32; msk <<= 1) m = fmaxf(m, __shfl_xor(m, msk));
            const float pe = __expf(s - m);
            float sum = pe;
            #pragma unroll
            for (int msk = 1; msk < 32; msk <<= 1) sum += __shfl_xor(sum, msk);
            const float pn = pe / sum;

            float o0 = 0.f, o1 = 0.f;
            #pragma unroll 8
            for (int c = 0; c < 32; c++) {
                const float pc = __shfl(pn, hw + c);
                const float2 v = *(const float2*)&dV[c * 64 + ln * 2];
                o0 += pc * v.x;
                o1 += pc * v.y;
            }
            float2 o2; o2.x = o0; o2.y = o1;
            *(float2*)(wsI + ((size_t)(b * 32 + row) * NH + h) * NE + ln * 2) = o2;
        }
        return;
    }

    // ================= INTRA block: (b, h, tile-of-32-rows), MFMA ===========
    const int ib   = bid - 128;
    const int tile = ib & 3;
    const int h    = (ib >> 2) & 7;
    const int b    = ib >> 5;
    const int r0   = tile * 32;

    // ---- 1. stage K,Q (bf16 row-major) + V^T (bf16); loads batched first ----
    {
        const float* kg = kT + ((size_t)b * 128 * NH + h) * NE;
        const float* vg = vT + ((size_t)b * 128 * NH + h) * NE;
        const float* qg = qT + ((size_t)(b * 128 + r0) * NH + h) * NE;

        float4 kr[8], vr[8], qr[2];
        #pragma unroll
        for (int i = 0; i < 8; i++) {
            const int idx = tid + i * 256;
            const int row = idx >> 4, f = (idx & 15) * 4;
            kr[i] = *(const float4*)(kg + (size_t)row * ROWSTRIDE + f);
        }
        #pragma unroll
        for (int i = 0; i < 8; i++) {
            const int idx = tid + i * 256;
            const int row = idx >> 4, f = (idx & 15) * 4;
            vr[i] = *(const float4*)(vg + (size_t)row * ROWSTRIDE + f);
        }
        #pragma unroll
        for (int i = 0; i < 2; i++) {
            const int idx = tid + i * 256;
            const int row = idx >> 4, f = (idx & 15) * 4;
            qr[i] = *(const float4*)(qg + (size_t)row * ROWSTRIDE + f);
        }

        unsigned short* wKb = (unsigned short*)smem;            // [128][72]
        #pragma unroll
        for (int i = 0; i < 8; i++) {
            const int idx = tid + i * 256;
            const int row = idx >> 4, f = (idx & 15) * 4;
            ushort4 pk; pk.x = f2bf(kr[i].x); pk.y = f2bf(kr[i].y);
            pk.z = f2bf(kr[i].z); pk.w = f2bf(kr[i].w);
            *(ushort4*)(wKb + row * 72 + f) = pk;
        }
        unsigned short* wQb = (unsigned short*)(smem + OFF_QB); // [32][72]
        #pragma unroll
        for (int i = 0; i < 2; i++) {
            const int idx = tid + i * 256;
            const int row = idx >> 4, f = (idx & 15) * 4;
            ushort4 pk; pk.x = f2bf(qr[i].x); pk.y = f2bf(qr[i].y);
            pk.z = f2bf(qr[i].z); pk.w = f2bf(qr[i].w);
            *(ushort4*)(wQb + row * 72 + f) = pk;
        }
        unsigned short* wVb = (unsigned short*)(smem + OFF_VB); // [64][136] = V^T
        #pragma unroll
        for (int i = 0; i < 8; i++) {
            const int idx = tid + i * 256;
            const int c = idx >> 4, f = (idx & 15) * 4;
            const float arr[4] = { vr[i].x, vr[i].y, vr[i].z, vr[i].w };
            #pragma unroll
            for (int u = 0; u < 4; u++) {
                const int j = (c + u) & 3;          // rotate to spread banks
                wVb[(f + j) * 136 + c] = f2bf(arr[j]);
            }
        }
    }
    __syncthreads();

    // ---- 2. MFMA scores: D(32x128) = Q(32x64) . K^T(64x128) ----
    const int lane = tid & 63;
    const int ln15 = lane & 15;
    const int quad = lane >> 4;
    const int w    = tid >> 6;      // wave 0..3
    const int mt   = w & 1;         // M-tile (16 q-rows)
    const int ntb  = (w >> 1) * 4;  // first of 4 N-tiles (16 kv-rows each)

    vf4 accS[4];
    #pragma unroll
    for (int t = 0; t < 4; t++) accS[t] = (vf4){0.f, 0.f, 0.f, 0.f};
    {
        const unsigned short* sKb = (const unsigned short*)smem;
        const unsigned short* sQb = (const unsigned short*)(smem + OFF_QB);
        #pragma unroll
        for (int kt = 0; kt < 2; kt++) {
            const v8s aQ = *(const v8s*)(sQb + (mt * 16 + ln15) * 72 + kt * 32 + quad * 8);
            #pragma unroll
            for (int t = 0; t < 4; t++) {
                const v8s bK = *(const v8s*)(sKb + ((ntb + t) * 16 + ln15) * 72 + kt * 32 + quad * 8);
                accS[t] = __builtin_amdgcn_mfma_f32_16x16x32_bf16(aQ, bK, accS[t], 0, 0, 0);
            }
        }
    }
    __syncthreads();   // all frag reads done; region1 dead -> becomes sS

    // ---- 3. scatter scaled scores to sS fp32[32][132] (C-layout) ----
    {
        float* sS = (float*)smem;
        #pragma unroll
        for (int t = 0; t < 4; t++)
            #pragma unroll
            for (int reg = 0; reg < 4; reg++)
                sS[(mt * 16 + quad * 4 + reg) * 132 + (ntb + t) * 16 + ln15]
                    = accS[t][reg] * 0.125f;
    }
    __syncthreads();

    // ---- 4. softmax (fp32) -> normalized P bf16[32][136] ----
    {
        const float* sS = (const float*)smem;
        unsigned short* sP = (unsigned short*)(smem + OFF_P);
        const int r   = tid >> 3;
        const int sub = tid & 7;
        float vals[16];
        const float* Srow = sS + r * 132 + sub * 16;
        #pragma unroll
        for (int c4 = 0; c4 < 4; c4++) {
            const float4 v = *(const float4*)(Srow + c4 * 4);
            vals[c4*4+0] = v.x; vals[c4*4+1] = v.y; vals[c4*4+2] = v.z; vals[c4*4+3] = v.w;
        }
        float m = vals[0];
        #pragma unroll
        for (int i = 1; i < 16; i++) m = fmaxf(m, vals[i]);
        #pragma unroll
        for (int msk = 1; msk < 8; msk <<= 1) m = fmaxf(m, __shfl_xor(m, msk));
        float s = 0.f;
        #pragma unroll
        for (int i = 0; i < 16; i++) { vals[i] = __expf(vals[i] - m); s += vals[i]; }
        #pragma unroll
        for (int msk = 1; msk < 8; msk <<= 1) s += __shfl_xor(s, msk);
        const float inv = 1.f / s;
        #pragma unroll
        for (int c4 = 0; c4 < 4; c4++) {
            ushort4 pk;
            pk.x = f2bf(vals[c4*4+0] * inv); pk.y = f2bf(vals[c4*4+1] * inv);
            pk.z = f2bf(vals[c4*4+2] * inv); pk.w = f2bf(vals[c4*4+3] * inv);
            *(ushort4*)(sP + r * 136 + sub * 16 + c4 * 4) = pk;
        }
    }
    __syncthreads();

    // ---- 5. MFMA PV: O(32x64) = P(32x128) . V(128x64) -> wsT ----
    {
        const unsigned short* sVb = (const unsigned short*)(smem + OFF_VB);
        const unsigned short* sP  = (const unsigned short*)(smem + OFF_P);
        const int neb = (w >> 1) * 2;   // first of 2 N-tiles (16 e each)

        vf4 accO[2];
        accO[0] = (vf4){0.f, 0.f, 0.f, 0.f};
        accO[1] = (vf4){0.f, 0.f, 0.f, 0.f};
        #pragma unroll
        for (int kt = 0; kt < 4; kt++) {
            const v8s aP = *(const v8s*)(sP + (mt * 16 + ln15) * 136 + kt * 32 + quad * 8);
            #pragma unroll
            for (int t = 0; t < 2; t++) {
                const v8s bV = *(const v8s*)(sVb + ((neb + t) * 16 + ln15) * 136 + kt * 32 + quad * 8);
                accO[t] = __builtin_amdgcn_mfma_f32_16x16x32_bf16(aP, bV, accO[t], 0, 0, 0);
            }
        }
        #pragma unroll
        for (int t = 0; t < 2; t++) {
            const int e = (neb + t) * 16 + ln15;
            #pragma unroll
            for (int reg = 0; reg < 4; reg++) {
                const int row = r0 + mt * 16 + quad * 4 + reg;
                wsT[((size_t)(b * 128 + row) * NH + h) * NE + e] = accO[t][reg];
            }
        }
    }
}

// out[b, pi*32+j, h, :] = wsT[b, pi, h, :] + wsI[b, pi>>2, h, :], j in [0,32).
// Wave lanes span (h, e4) -> every store instruction is 1 KB contiguous.
__global__ __launch_bounds__(256) void duplicate_add_kernel(
    const float4* __restrict__ wsT, const float4* __restrict__ wsI,
    float* __restrict__ out)
{
    const int t  = blockIdx.x * 256 + threadIdx.x;   // 0 .. 262143
    const int e4 = t & 15;
    const int h  = (t >> 4) & 7;
    const int pi = (t >> 7) & 127;
    const int b  = t >> 14;

    const float4 a = wsT[((b * 128 + pi) * NH + h) * 16 + e4];
    const float4 c = wsI[((b * 32 + (pi >> 2)) * NH + h) * 16 + e4];
    vf4 s; s.x = a.x + c.x; s.y = a.y + c.y; s.z = a.z + c.z; s.w = a.w + c.w;

    float* o = out + ((((size_t)b * 4096 + pi * 32) * NH + h) * 16 + e4) * 4;
    #pragma unroll
    for (int j = 0; j < 32; j++)
        __builtin_nontemporal_store(s, (vf4*)(o + (size_t)j * ROWSTRIDE));
}

extern "C" void kernel_launch(void* const* d_in, const int* in_sizes, int n_in,
                              void* d_out, int out_size, void* d_ws, size_t ws_size,
                              hipStream_t stream) {
    const float* q_inter = (const float*)d_in[0];
    const float* k_inter = (const float*)d_in[1];
    const float* v_inter = (const float*)d_in[2];
    const float* q_intra = (const float*)d_in[3];
    const float* k_intra = (const float*)d_in[4];
    const float* v_intra = (const float*)d_in[5];
    float* out = (float*)d_out;
    float* wsT = (float*)d_ws;                        // V_intra: [16,128,8,64] = 4 MiB
    float* wsI = wsT + (size_t)16 * 128 * NH * NE;    // V_inter: [16,32,8,64]  = 1 MiB

    // Heterogeneous grid: 128 inter blocks + 512 intra blocks, all co-resident.
    attn_split<<<640, 256, 0, stream>>>(
        q_inter, k_inter, v_inter, q_intra, k_intra, v_intra, wsT, wsI);

    // Duplicate + add sweep -> out. 1024 blocks, 32 streaming stores/thread.
    duplicate_add_kernel<<<1024, 256, 0, stream>>>(
        (const float4*)wsT, (const float4*)wsI, out);
}